// Round 17
// baseline (358.636 us; speedup 1.0000x reference)
//
#include <hip/hip_runtime.h>
#include <hip/hip_bf16.h>
#include <hip/hip_fp8.h>
#include <math.h>

#define M_TOT 4096
#define K_TOT 1024
#define V_TOT 32000

typedef int int4v __attribute__((ext_vector_type(4)));
typedef int int8v __attribute__((ext_vector_type(8)));
typedef float f32x4 __attribute__((ext_vector_type(4)));

__device__ __forceinline__ void gload_lds16(const void* g, void* l) {
  __builtin_amdgcn_global_load_lds(
      (const __attribute__((address_space(1))) void*)g,
      (__attribute__((address_space(3))) void*)l, 16, 0, 0);
}

__device__ __forceinline__ float sani(float v) {
  return (v != v) ? 0.0f : fminf(fmaxf(v, -1e4f), 1e4f);
}

__device__ __forceinline__ int pk4_fp8(float a, float b, float c, float d) {
#if __has_builtin(__builtin_amdgcn_cvt_pk_fp8_f32)
  int p = __builtin_amdgcn_cvt_pk_fp8_f32(a, b, 0, false);
  p = __builtin_amdgcn_cvt_pk_fp8_f32(c, d, p, true);
  return p;
#else
  union { unsigned char b4[4]; int i; } u;
  u.b4[0] = __hip_fp8_e4m3(a).__x;
  u.b4[1] = __hip_fp8_e4m3(b).__x;
  u.b4[2] = __hip_fp8_e4m3(c).__x;
  u.b4[3] = __hip_fp8_e4m3(d).__x;
  return u.i;
#endif
}

// merged prep: blocks [0,4096) do hidden_states, [4096,36096) do weights.
__global__ void prep_hw(const float* __restrict__ h, const float* __restrict__ w,
                        unsigned char* __restrict__ h8, unsigned char* __restrict__ w8,
                        float* __restrict__ h0, float* __restrict__ wtime) {
  __shared__ float red[4];
  __shared__ float r_sh;
  const int b = blockIdx.x;
  const int t = threadIdx.x;
  if (b < M_TOT) {
    const int m = b;
    const float* row = h + (long)m * (K_TOT + 1);
    if (t == 0) h0[m] = sani(row[0]);
    float4 x = *(const float4*)(row + 1 + t * 4);
    ((int*)(h8 + (long)m * K_TOT))[t] =
        pk4_fp8(sani(x.x), sani(x.y), sani(x.z), sani(x.w));
  } else {
    const int v = b - M_TOT;
    const float* row = w + (long)v * K_TOT;
    float4 x = *(const float4*)(row + t * 4);
    float s = x.x * x.x + x.y * x.y + x.z * x.z + x.w * x.w;
#pragma unroll
    for (int off = 32; off > 0; off >>= 1) s += __shfl_down(s, off);
    int lane = t & 63, wv = t >> 6;
    if (lane == 0) red[wv] = s;
    __syncthreads();
    if (t == 0) {
      float tot = red[0] + red[1] + red[2] + red[3];
      float norm = sqrtf(tot);
      float r = (norm > 1e-7f) ? (sinhf(norm) / fmaxf(norm, 1e-7f)) : 1.0f;
      r_sh = r;
      wtime[v] = coshf(norm);
    }
    __syncthreads();
    float sc = 16.0f * r_sh;  // 16x prescale; undone by MFMA scaleA = 2^-4
    ((int*)(w8 + (long)v * K_TOT))[t] =
        pk4_fp8(sc * x.x, sc * x.y, sc * x.z, sc * x.w);
  }
}

// ====== 128x256 tile, BK=128, MX-fp8: A-in-LDS + B-from-L2, 2 blocks/CU ====
// r16 post-mortem: MFMA floor is 57us (fp8, irreducible); HBM ran at ~48%
// of achievable because 1 block/CU + counted-window keeps only ~8-16KB in
// flight (need ~22KB/CU for 900cy latency) and epilogue/prologue bursts are
// naked. Fix: B fragments are plain row-chunks -> stream them from global
// (L2-resident panels) per-lane; LDS holds only A (2 x 16KB dbuf) -> 2
// independent 256-thread blocks/CU at an UN-halved-tile-economics geometry
// (B never staged; A-tile per output row unchanged).
// Per-iter schedule (1 barrier, 2 counted waits; ledger verified):
//   issue bv(kt): 16 global dwordx4 (no LDS - safe anywhere)
//   VM16  -> outstanding = bv(kt); proves stage(kt) landed (all waves': each
//            wave passes its own VM16 before BAR)
//   BAR
//   STAGE(kt+1) -> buf (kt+1)&1  [interval reads hit buf kt&1 - disjoint]
//   ds_read af(kt) from buf kt&1
//   VM4   -> outstanding = stage(kt+1); proves bv(kt) landed
//   32 MFMA (setprio-wrapped)
// Write-after-read: buf(kt+1) was last read in interval [BAR_{kt-1},BAR_kt],
// consumed before those waves passed BAR_kt; stage issues after BAR_kt. OK.
// A-swizzle (zero-conflict, proven r11-r16): slot chunk c = global chunk
// c^(row&7), source pre-swizzled cc=(t&7)^((t>>3)&7), read (2fq+h)^(fr&7).
// B from global needs NO swizzle (no banks) and NO transpose (fragment =
// 32 contiguous bytes per lane at row(fr)-major addressing).
// Registers: acc 128 + bv 64 + af 32 + addr ~20 = ~245 <= 256 cap at
// launch_bounds(256,2) (2 waves/SIMD x 2 blocks). wt/h0 loads deferred to
// epilogue to stay under cap. If this spills -> scratch traffic -> revert.
// Grid 4000 = 125 v-panels x 32 m-tiles, XCD-bijective; m-half-major group
// order keeps one 2MB A-half + ~4 B-panels (1MB) resident per XCD L2.
#define BAR __builtin_amdgcn_s_barrier()
#define VM16 asm volatile("s_waitcnt vmcnt(16)" ::: "memory")
#define VM4 asm volatile("s_waitcnt vmcnt(4)" ::: "memory")

__global__ __launch_bounds__(256, 2) void gemm_geo(
    const unsigned char* __restrict__ h8, const unsigned char* __restrict__ w8,
    const float* __restrict__ h0, const float* __restrict__ wtime,
    const float* __restrict__ ls, float* __restrict__ out) {
  __shared__ __align__(16) char smem[32768];  // 2 x 16KB A buffers

  const int t = threadIdx.x;
  const int wave = t >> 6, lane = t & 63;
  const int fr = lane & 15, fq = lane >> 4;
  const int wm = wave >> 1, wn = wave & 1;  // 2 (M) x 2 (N) wave grid

  // XCD-bijective: swz = per-XCD contiguous chunk; group g = 16 blocks
  // (one (panel, m-half) pair); m-half-major across panels so an XCD's
  // concurrent ~4 groups share ONE A-half (2MB) + ~4 panels (1MB) in L2.
  const int bid = blockIdx.x;
  const int swz = (bid & 7) * 500 + (bid >> 3);
  const int g = swz >> 4;                  // [0,250)
  const int sub = swz & 15;                // m-tile within half
  const int half = (g >= 125) ? 1 : 0;
  const int tile_v = g - half * 125;       // [0,125)
  const int tile_m = half * 16 + sub;      // [0,32)
  const int row0 = tile_m * 128;
  const int col0 = tile_v * 256;

  // ---- A (LDS) lane constants ----
  const int xorv = fr & 7;
  const int c0 = ((2 * fq) ^ xorv) * 16;
  const int c1 = ((2 * fq + 1) ^ xorv) * 16;
  const int a_rd = (wm * 64 + fr) * 128;  // + buf*16384 + im*2048

  // staging: thread t -> rows hh*32 + (t>>3), slot chunk t&7, pre-swizzled
  const int cc = (t & 7) ^ ((t >> 3) & 7);
  const unsigned char* pA = h8 + ((long)row0 + (t >> 3)) * K_TOT + cc * 16;
  const int dst_w = wave * 1024;  // wave-uniform; HW adds lane*16

  auto STAGE = [&](int kt, int bufo) {
#pragma unroll
    for (int hh = 0; hh < 4; ++hh)
      gload_lds16(pA + (long)hh * (32L * K_TOT) + kt * 128,
                  smem + bufo + hh * 4096 + dst_w);
  };

  // ---- B (global) lane base: row = col0 + wn*128 + iv*16 + fr ----
  const unsigned char* pB =
      w8 + ((long)col0 + wn * 128 + fr) * K_TOT + fq * 32;

  f32x4 acc[4][8];
#pragma unroll
  for (int i = 0; i < 4; ++i)
#pragma unroll
    for (int j = 0; j < 8; ++j) acc[i][j] = (f32x4)(0.0f);

  // prologue: A tile0 -> buf0 (4 loads). Proven by iter0's VM16.
  STAGE(0, 0);

#pragma unroll 1
  for (int kt = 0; kt < 8; ++kt) {
    const int cbo = (kt & 1) << 14;
    const int nbo = cbo ^ 16384;
    const int skt = (kt + 1 < 8) ? kt + 1 : 7;  // clamped redundant tail

    // issue bv(kt): 16 dwordx4 (2 per iv fragment), no LDS involvement
    int4v blo[8], bhi[8];
#pragma unroll
    for (int iv = 0; iv < 8; ++iv) {
      const unsigned char* pb = pB + (long)iv * (16L * K_TOT) + kt * 128;
      blo[iv] = *(const int4v*)pb;
      bhi[iv] = *(const int4v*)(pb + 16);
    }

    VM16;  // proves stage(kt) (outstanding = the 16 bv loads just issued)
    BAR;

    STAGE(skt, nbo);  // A(kt+1) -> other buffer (disjoint from reads)

    int8v av[4];
#pragma unroll
    for (int im = 0; im < 4; ++im) {
      int4v lo = *(const int4v*)(smem + cbo + a_rd + im * 2048 + c0);
      int4v hi = *(const int4v*)(smem + cbo + a_rd + im * 2048 + c1);
      av[im] = (int8v){lo[0], lo[1], lo[2], lo[3], hi[0], hi[1], hi[2], hi[3]};
    }

    VM4;  // outstanding = stage(kt+1); proves bv(kt) landed

    __builtin_amdgcn_s_setprio(1);
#pragma unroll
    for (int im = 0; im < 4; ++im)
#pragma unroll
      for (int iv = 0; iv < 8; ++iv) {
        int8v bv = (int8v){blo[iv][0], blo[iv][1], blo[iv][2], blo[iv][3],
                           bhi[iv][0], bhi[iv][1], bhi[iv][2], bhi[iv][3]};
        acc[im][iv] = __builtin_amdgcn_mfma_scale_f32_16x16x128_f8f6f4(
            bv, av[im], acc[im][iv], 0, 0, 0, 0x7B7B7B7B, 0, 0x7F7F7F7F);
      }
    __builtin_amdgcn_s_setprio(0);
  }

  // fused epilogue: x = h0*w_time - dot; d2 = acosh(x)^2; out = -tau*d2.
  // wt/h0 loaded here (not pre-loop) to stay under the 256-VGPR cap.
  // Per row: 8 f32x4 computed then 8 nt stores back-to-back (full 128B
  // lines - r16's write-combine fix).
  const float ntau = -fminf(fmaxf(ls[0], 0.01f), 2.5f);
  const float LN2 = 0.69314718055994531f;
  f32x4 wt4[8];
#pragma unroll
  for (int iv = 0; iv < 8; ++iv)
    wt4[iv] = *(const f32x4*)&wtime[col0 + wn * 128 + iv * 16 + fq * 4];
#pragma unroll
  for (int im = 0; im < 4; ++im) {
    const float hh = h0[row0 + wm * 64 + im * 16 + fr];
    float* orow = out + (long)(row0 + wm * 64 + im * 16 + fr) * V_TOT + col0 +
                  wn * 128;
    f32x4 rv[8];
#pragma unroll
    for (int iv = 0; iv < 8; ++iv) {
#pragma unroll
      for (int j = 0; j < 4; ++j) {
        float x = fmaf(hh, wt4[iv][j], -acc[im][iv][j]);
        float xm1 = fmaxf(x - 1.0f, 0.0f);
        float arg = fmaxf(fmaf(x, x, -1.0f), 0.0f);
        float lg2 = __builtin_amdgcn_logf(x + __builtin_amdgcn_sqrtf(arg));
        float dex = LN2 * lg2;
        float d2_exact = dex * dex;
        float ts = fmaf(xm1, -1.0f / 12.0f, 1.0f);
        float d2_tay = 2.0f * xm1 * ts * ts;
        float d2 = (xm1 < 1e-3f) ? d2_tay : d2_exact;
        rv[iv][j] = ntau * d2;
      }
    }
#pragma unroll
    for (int iv = 0; iv < 8; ++iv)
      __builtin_nontemporal_store(rv[iv], (f32x4*)(orow + iv * 16 + fq * 4));
  }
}

extern "C" void kernel_launch(void* const* d_in, const int* in_sizes, int n_in,
                              void* d_out, int out_size, void* d_ws, size_t ws_size,
                              hipStream_t stream) {
  const float* h = (const float*)d_in[0];   // [2,2048,1025]
  const float* w = (const float*)d_in[1];   // [32000,1024]
  const float* ls = (const float*)d_in[2];  // scalar
  float* out = (float*)d_out;               // [2,2048,32000] fp32

  char* ws = (char*)d_ws;
  unsigned char* w8 = (unsigned char*)ws;                     // 32,768,000 B
  unsigned char* h8 = (unsigned char*)(ws + 32768000);        // 4,194,304 B
  float* wtime = (float*)(ws + 32768000 + 4194304);           // 128,000 B
  float* h0 = (float*)(ws + 32768000 + 4194304 + 128000);     // 16,384 B

  prep_hw<<<M_TOT + V_TOT, 256, 0, stream>>>(h, w, h8, w8, h0, wtime);
  gemm_geo<<<4000, 256, 0, stream>>>(h8, w8, h0, wtime, ls, out);
}

// Round 18
// 268.099 us; speedup vs baseline: 1.3377x; 1.3377x over previous
//
#include <hip/hip_runtime.h>
#include <hip/hip_bf16.h>
#include <hip/hip_fp8.h>
#include <math.h>

#define M_TOT 4096
#define K_TOT 1024
#define V_TOT 32000

typedef int int4v __attribute__((ext_vector_type(4)));
typedef int int8v __attribute__((ext_vector_type(8)));
typedef float f32x4 __attribute__((ext_vector_type(4)));

__device__ __forceinline__ void gload_lds16(const void* g, void* l) {
  __builtin_amdgcn_global_load_lds(
      (const __attribute__((address_space(1))) void*)g,
      (__attribute__((address_space(3))) void*)l, 16, 0, 0);
}

__device__ __forceinline__ float sani(float v) {
  return (v != v) ? 0.0f : fminf(fmaxf(v, -1e4f), 1e4f);
}

__device__ __forceinline__ int pk4_fp8(float a, float b, float c, float d) {
#if __has_builtin(__builtin_amdgcn_cvt_pk_fp8_f32)
  int p = __builtin_amdgcn_cvt_pk_fp8_f32(a, b, 0, false);
  p = __builtin_amdgcn_cvt_pk_fp8_f32(c, d, p, true);
  return p;
#else
  union { unsigned char b4[4]; int i; } u;
  u.b4[0] = __hip_fp8_e4m3(a).__x;
  u.b4[1] = __hip_fp8_e4m3(b).__x;
  u.b4[2] = __hip_fp8_e4m3(c).__x;
  u.b4[3] = __hip_fp8_e4m3(d).__x;
  return u.i;
#endif
}

// merged prep: blocks [0,4096) do hidden_states, [4096,36096) do weights.
__global__ void prep_hw(const float* __restrict__ h, const float* __restrict__ w,
                        unsigned char* __restrict__ h8, unsigned char* __restrict__ w8,
                        float* __restrict__ h0, float* __restrict__ wtime) {
  __shared__ float red[4];
  __shared__ float r_sh;
  const int b = blockIdx.x;
  const int t = threadIdx.x;
  if (b < M_TOT) {
    const int m = b;
    const float* row = h + (long)m * (K_TOT + 1);
    if (t == 0) h0[m] = sani(row[0]);
    float4 x = *(const float4*)(row + 1 + t * 4);
    ((int*)(h8 + (long)m * K_TOT))[t] =
        pk4_fp8(sani(x.x), sani(x.y), sani(x.z), sani(x.w));
  } else {
    const int v = b - M_TOT;
    const float* row = w + (long)v * K_TOT;
    float4 x = *(const float4*)(row + t * 4);
    float s = x.x * x.x + x.y * x.y + x.z * x.z + x.w * x.w;
#pragma unroll
    for (int off = 32; off > 0; off >>= 1) s += __shfl_down(s, off);
    int lane = t & 63, wv = t >> 6;
    if (lane == 0) red[wv] = s;
    __syncthreads();
    if (t == 0) {
      float tot = red[0] + red[1] + red[2] + red[3];
      float norm = sqrtf(tot);
      float r = (norm > 1e-7f) ? (sinhf(norm) / fmaxf(norm, 1e-7f)) : 1.0f;
      r_sh = r;
      wtime[v] = coshf(norm);
    }
    __syncthreads();
    float sc = 16.0f * r_sh;  // 16x prescale; undone by MFMA scaleA = 2^-4
    ((int*)(w8 + (long)v * K_TOT))[t] =
        pk4_fp8(sc * x.x, sc * x.y, sc * x.z, sc * x.w);
  }
}

// == 128x256 tile, BK=128 MX-fp8: A-dbuf(2x16K) + B-sgl(32K) = 64KB LDS,
// == 2 independent blocks/CU.
// r17 lessons applied: keep fragments in LDS with just-before-MFMA reads
// (B-in-registers blew the VGPR budget); keep r17's grid map (FETCH=42MB,
// best measured). r16 lessons kept: batched nt stores (full 128B lines),
// counted vmcnt, zero-conflict swizzle, fp8 economics.
// Why B single-buffer needs NO drain: per iter, bv reads happen FIRST, the
// read-seal BAR follows, then B(kt+1) stages into the same buffer and is
// only proven at iter END (VM4, after 32 MFMA ~ >900cy) -> latency hidden.
// Ledger: end-of-iter outstanding = carried A(kt+1)[4] + B(kt+1)[8] +
// A(kt+2)[4] = 16; VM4 proves first 12 = A(kt+1),B(kt+1); A(kt+2) flies.
// Prologue: A(0)[4]+B(0)[8]+A(1)[4] -> VM4 proves A0,B0. 2 barriers/iter.
// Write-after-read safety: B restage after the read-seal BAR; A restage
// targets buf (kt+2)&1 = buf just read this iter, also sealed. ds_reads
// feeding MFMA are lgkm-counted by compiler before each wave's BAR arrival.
// LDS layout: A: buf*16384 + row*128 + c*16 (rows 0..127); B: 32768 +
// row*128 + c*16 (rows 0..255). Swizzle (0-conflict, r11-r16): slot chunk
// c = global chunk c^(row&7); source pre-swizzled cc=(t&7)^((t>>3)&7);
// read chunks (2fq+h)^(fr&7).
// Registers: acc[4][8]=128 (AGPR) + bv 64 + av 32 short-lived -> ~128 VGPR.
// launch_bounds(256,2): 2 blocks/CU (each 4 waves, 1 wave/SIMD/block).
#define BAR __builtin_amdgcn_s_barrier()
#define LGKM0 asm volatile("s_waitcnt lgkmcnt(0)" ::: "memory")
#define VM4 asm volatile("s_waitcnt vmcnt(4)" ::: "memory")

__global__ __launch_bounds__(256, 2) void gemm_geo(
    const unsigned char* __restrict__ h8, const unsigned char* __restrict__ w8,
    const float* __restrict__ h0, const float* __restrict__ wtime,
    const float* __restrict__ ls, float* __restrict__ out) {
  __shared__ __align__(16) char smem[65536];  // A: 2x16KB | B: 32KB @32768

  const int t = threadIdx.x;
  const int wave = t >> 6, lane = t & 63;
  const int fr = lane & 15, fq = lane >> 4;
  const int wm = wave >> 1, wn = wave & 1;  // 2 (M) x 2 (N) wave grid

  // r17 grid map (FETCH=42MB): per-XCD contiguous chunks; 16-block groups
  // share (B-panel 256KB, A-half 2MB); m-half-major across panels.
  const int bid = blockIdx.x;
  const int swz = (bid & 7) * 500 + (bid >> 3);
  const int g = swz >> 4;                  // [0,250)
  const int sub = swz & 15;
  const int half = (g >= 125) ? 1 : 0;
  const int tile_v = g - half * 125;       // [0,125)
  const int tile_m = half * 16 + sub;      // [0,32)
  const int row0 = tile_m * 128;
  const int col0 = tile_v * 256;

  // read-side lane constants (bytes)
  const int xorv = fr & 7;
  const int c0 = ((2 * fq) ^ xorv) * 16;
  const int c1 = ((2 * fq + 1) ^ xorv) * 16;
  const int a_rd = (wm * 64 + fr) * 128;            // + buf*16384 + im*2048
  const int b_rd = 32768 + (wn * 128 + fr) * 128;   // + iv*2048

  auto RDF = [&](int off) -> int8v {
    int4v lo = *(const int4v*)(smem + off + c0);
    int4v hi = *(const int4v*)(smem + off + c1);
    return (int8v){lo[0], lo[1], lo[2], lo[3], hi[0], hi[1], hi[2], hi[3]};
  };

  // staging: thread t -> row (t>>3) within 32-row batch, slot chunk t&7,
  // source pre-swizzled (rule #21: gload_lds writes linearly)
  const int cc = (t & 7) ^ ((t >> 3) & 7);
  const unsigned char* pA = h8 + ((long)row0 + (t >> 3)) * K_TOT + cc * 16;
  const unsigned char* pB = w8 + ((long)col0 + (t >> 3)) * K_TOT + cc * 16;
  const int dst_w = wave * 1024;  // wave-uniform; HW adds lane*16

  auto STAGE_A = [&](int kt, int bufo) {
#pragma unroll
    for (int hh = 0; hh < 4; ++hh)
      gload_lds16(pA + (long)hh * (32L * K_TOT) + kt * 128,
                  smem + bufo + hh * 4096 + dst_w);
  };
  auto STAGE_B = [&](int kt) {
#pragma unroll
    for (int hh = 0; hh < 8; ++hh)
      gload_lds16(pB + (long)hh * (32L * K_TOT) + kt * 128,
                  smem + 32768 + hh * 4096 + dst_w);
  };

  f32x4 acc[4][8];
#pragma unroll
  for (int i = 0; i < 4; ++i)
#pragma unroll
    for (int j = 0; j < 8; ++j) acc[i][j] = (f32x4)(0.0f);

  // prologue: A(0)->buf0 [4], B(0) [8], A(1)->buf1 [4]; VM4 proves A0+B0.
  STAGE_A(0, 0);
  STAGE_B(0);
  STAGE_A(1, 16384);
  VM4;
  BAR;

#pragma unroll 1
  for (int kt = 0; kt < 8; ++kt) {
    const int cbo = (kt & 1) << 14;
    const int skB = (kt + 1 < 8) ? kt + 1 : 7;  // clamped redundant tail
    const int skA = (kt + 2 < 8) ? kt + 2 : 7;

    int8v bv[8], av[4];
#pragma unroll
    for (int iv = 0; iv < 8; ++iv) bv[iv] = RDF(b_rd + iv * 2048);
#pragma unroll
    for (int im = 0; im < 4; ++im) av[im] = RDF(cbo + a_rd + im * 2048);
    LGKM0;
    __builtin_amdgcn_sched_barrier(0);
    BAR;  // all waves sealed their B + A(kt) reads

    STAGE_B(skB);        // B(kt+1) -> the single B buffer
    STAGE_A(skA, cbo);   // A(kt+2) -> the A buffer just read

    __builtin_amdgcn_s_setprio(1);
#pragma unroll
    for (int im = 0; im < 4; ++im)
#pragma unroll
      for (int iv = 0; iv < 8; ++iv)
        acc[im][iv] = __builtin_amdgcn_mfma_scale_f32_16x16x128_f8f6f4(
            bv[iv], av[im], acc[im][iv], 0, 0, 0, 0x7B7B7B7B, 0, 0x7F7F7F7F);
    __builtin_amdgcn_s_setprio(0);

    // carried A(kt+1)[4] + B(kt+1)[8] + A(kt+2)[4] = 16 outstanding;
    // VM4 proves A(kt+1)+B(kt+1); A(kt+2)'s 4 stay in flight.
    VM4;
    BAR;
  }

  // fused epilogue: x = h0*w_time - dot; d2 = acosh(x)^2; out = -tau*d2.
  // Per row: 8 f32x4 computed, then 8 nt stores back-to-back (full 128B
  // lines, r16's write-combine fix). Co-resident block hides the drain.
  const float ntau = -fminf(fmaxf(ls[0], 0.01f), 2.5f);
  const float LN2 = 0.69314718055994531f;
  f32x4 wt4[8];
#pragma unroll
  for (int iv = 0; iv < 8; ++iv)
    wt4[iv] = *(const f32x4*)&wtime[col0 + wn * 128 + iv * 16 + fq * 4];
#pragma unroll
  for (int im = 0; im < 4; ++im) {
    const float hh = h0[row0 + wm * 64 + im * 16 + fr];
    float* orow = out + (long)(row0 + wm * 64 + im * 16 + fr) * V_TOT + col0 +
                  wn * 128;
    f32x4 rv[8];
#pragma unroll
    for (int iv = 0; iv < 8; ++iv) {
#pragma unroll
      for (int j = 0; j < 4; ++j) {
        float x = fmaf(hh, wt4[iv][j], -acc[im][iv][j]);
        float xm1 = fmaxf(x - 1.0f, 0.0f);
        float arg = fmaxf(fmaf(x, x, -1.0f), 0.0f);
        float lg2 = __builtin_amdgcn_logf(x + __builtin_amdgcn_sqrtf(arg));
        float dex = LN2 * lg2;
        float d2_exact = dex * dex;
        float ts = fmaf(xm1, -1.0f / 12.0f, 1.0f);
        float d2_tay = 2.0f * xm1 * ts * ts;
        float d2 = (xm1 < 1e-3f) ? d2_tay : d2_exact;
        rv[iv][j] = ntau * d2;
      }
    }
#pragma unroll
    for (int iv = 0; iv < 8; ++iv)
      __builtin_nontemporal_store(rv[iv], (f32x4*)(orow + iv * 16 + fq * 4));
  }
}

extern "C" void kernel_launch(void* const* d_in, const int* in_sizes, int n_in,
                              void* d_out, int out_size, void* d_ws, size_t ws_size,
                              hipStream_t stream) {
  const float* h = (const float*)d_in[0];   // [2,2048,1025]
  const float* w = (const float*)d_in[1];   // [32000,1024]
  const float* ls = (const float*)d_in[2];  // scalar
  float* out = (float*)d_out;               // [2,2048,32000] fp32

  char* ws = (char*)d_ws;
  unsigned char* w8 = (unsigned char*)ws;                     // 32,768,000 B
  unsigned char* h8 = (unsigned char*)(ws + 32768000);        // 4,194,304 B
  float* wtime = (float*)(ws + 32768000 + 4194304);           // 128,000 B
  float* h0 = (float*)(ws + 32768000 + 4194304 + 128000);     // 16,384 B

  prep_hw<<<M_TOT + V_TOT, 256, 0, stream>>>(h, w, h8, w8, h0, wtime);
  gemm_geo<<<4000, 256, 0, stream>>>(h8, w8, h0, wtime, ls, out);
}